// Round 3
// baseline (249.684 us; speedup 1.0000x reference)
//
#include <hip/hip_runtime.h>
#include <stdint.h>

typedef short bf16x8 __attribute__((ext_vector_type(8)));
typedef float f32x16 __attribute__((ext_vector_type(16)));

#define LOG2E 1.44269504088896340736f
#define LN2f  0.69314718055994530942f

constexpr int Bn = 512;
constexpr int Ln = 2048;
constexpr int Cn = 32;
constexpr int NSEG = 64;      // 1024 scan units
constexpr int SEGLEN = 32;    // Ln / NSEG
constexpr int WARM = 16;
constexpr int NGRP = 16;      // Bn / 32
constexpr int WPB  = 4;       // waves per block
constexpr int DEPTH = 8;      // emission tile pipeline depth (per wave, in LDS)

// pack two f32 -> one VGPR of two bf16 (round-half-away via +0x8000, then take high halves)
__device__ __forceinline__ uint32_t pack2_bf16(float lo, float hi) {
    uint32_t a = __float_as_uint(lo) + 0x8000u;
    uint32_t b = __float_as_uint(hi) + 0x8000u;
    return __builtin_amdgcn_perm(b, a, 0x07060302u);
}

__device__ __forceinline__ void gload16(const float* g, float* l) {
    // async global->LDS, 16 B/lane, LDS dest = wave-uniform base + lane*16
    __builtin_amdgcn_global_load_lds(
        (__attribute__((address_space(1))) void*)g,
        (__attribute__((address_space(3))) void*)l,
        16, 0, 0);
}

// crf_scan: pure matrix scan. All scoring (tags/mask gathers) moved to crf_score.
//
// Memory redesign vs previous rounds: lane=batch made EVERY load a 32-line scatter
// (~170 line-touches/step) -> per-CU L1/TA request pipe saturated at ~1 step/1200cy
// regardless of wave count (rounds 0-2 evidence: warm LLC-resident dispatches same
// speed; 1 vs 4 waves/CU only 1.2x). Now: global_load_lds where each instr covers
// 8 batches x one full contiguous 128B row (16 fully-consumed lines/instr), tiles
// staged in per-wave LDS with read-side XOR swizzle pre-applied to the GLOBAL
// address (swizzle both-sides-or-neither).
//
// LDS tile (per wave, per slot): T[row=batch 0..31][8 x 16B chunks].
// Linear write: lane l, instr q -> row 8q+(l>>3), chunk l&7; global seg loaded =
// (l&7) ^ ((l>>3)&7)  => content(row, w) = global chunk (w ^ (row&7)).
// Fragment read (lane bl,h; q): wants global floats 4h+8q..+3 of row bl ->
// chunk (h+2q) ^ (bl&7). ds_read_b128, ~4-way bank conflict (acceptable).
__global__ __launch_bounds__(256, 1) void crf_scan(
    const float* __restrict__ emis, const float* __restrict__ trans,
    float* __restrict__ dDelta)
{
    __shared__ float ELDS[WPB][DEPTH][1024];   // 128 KiB
    const int lane = threadIdx.x & 63;
    const int wid  = threadIdx.x >> 6;
    const int h    = lane >> 5;
    const int bl   = lane & 31;
    const int bl7  = bl & 7;
    const int unit = blockIdx.x * WPB + wid;   // 0..1023
    const int g    = unit & (NGRP - 1);
    const int s    = unit >> 4;                // 0..NSEG-1
    const int b    = g * 32 + bl;

    // per-lane global base per load-instr q (pre-swizzled seg index)
    size_t gqb[4];
    {
        const int lr = lane >> 3;      // 0..7
        const int lc = lane & 7;       // 0..7
        #pragma unroll
        for (int q = 0; q < 4; ++q) {
            int br = 8 * q + lr;               // batch-in-group = LDS row
            int sg = lc ^ lr;                  // pre-swizzled 16B-chunk index
            gqb[q] = (size_t)(g * 32 + br) * Ln * Cn + (size_t)(sg * 4);
        }
    }

    // Constant A fragments: A[m=bl][k'], k' = 8h + j; col(j) = 4h + (j&3) + 8*(j>>2) (+16 for A2)
    bf16x8 A1, A2;
    {
        float e1[8], e2[8];
        #pragma unroll
        for (int j = 0; j < 8; ++j) {
            int c1 = 4 * h + (j & 3) + 8 * (j >> 2);
            e1[j] = __expf(trans[bl * Cn + c1]);
            e2[j] = __expf(trans[bl * Cn + c1 + 16]);
        }
        union { uint32_t u[4]; bf16x8 v; } ua, ub;
        #pragma unroll
        for (int q = 0; q < 4; ++q) {
            ua.u[q] = pack2_bf16(e1[2*q], e1[2*q+1]);
            ub.u[q] = pack2_bf16(e2[2*q], e2[2*q+1]);
        }
        A1 = ua.v; A2 = ub.v;
    }

    const f32x16 zeroC = {0.f,0.f,0.f,0.f,0.f,0.f,0.f,0.f,0.f,0.f,0.f,0.f,0.f,0.f,0.f,0.f};

    f32x16 Dv;
    bf16x8 B1, B2;
    float offF = 0.f;
    float adj  = 0.f;

    const int t0 = (s == 0) ? 0 : s * SEGLEN - WARM;
    const int nsteps = (s == 0) ? SEGLEN : (SEGLEN + WARM);

    auto issueTile = [&](int t, int slot) {
        #pragma unroll
        for (int q = 0; q < 4; ++q) {
            const float* gp = emis + gqb[q] + (size_t)t * Cn;
            gload16(gp, &ELDS[wid][slot][q * 256]);
        }
    };

    auto readFrag = [&](int slot, float4 (&bu)[4]) {
        #pragma unroll
        for (int q = 0; q < 4; ++q) {
            int c16 = (h + 2 * q) ^ bl7;
            bu[q] = *(const float4*)&ELDS[wid][slot][bl * 32 + c16 * 4];
        }
    };

    auto packB = [&]() {
        union { uint32_t u[4]; bf16x8 v; } p1, p2;
        #pragma unroll
        for (int q = 0; q < 4; ++q) {
            p1.u[q] = pack2_bf16(Dv[2*q],     Dv[2*q + 1]);
            p2.u[q] = pack2_bf16(Dv[8 + 2*q], Dv[8 + 2*q + 1]);
        }
        B1 = p1.v; B2 = p2.v;
    };

    auto pclamp = [&](int t) { return (t > Ln - 1) ? (Ln - 1) : t; };

    // consume tile #idx (slot idx&7): wait oldest 4 loads, read fragment,
    // scan-step, then refill the same slot with tile idx+DEPTH.
    auto stepConsume = [&](int idx, float a) {
        asm volatile("s_waitcnt vmcnt(28)" ::: "memory");
        float4 bu[4];
        readFrag(idx & (DEPTH - 1), bu);
        f32x16 acc = __builtin_amdgcn_mfma_f32_32x32x16_bf16(A1, B1, zeroC, 0, 0, 0);
        acc = __builtin_amdgcn_mfma_f32_32x32x16_bf16(A2, B2, acc, 0, 0, 0);
        #pragma unroll
        for (int q = 0; q < 4; ++q) {
            float x0 = exp2f(fmaf(bu[q].x, LOG2E, a));
            float x1 = exp2f(fmaf(bu[q].y, LOG2E, a));
            float x2 = exp2f(fmaf(bu[q].z, LOG2E, a));
            float x3 = exp2f(fmaf(bu[q].w, LOG2E, a));
            Dv[4*q+0] = acc[4*q+0] * x0;
            Dv[4*q+1] = acc[4*q+1] * x1;
            Dv[4*q+2] = acc[4*q+2] * x2;
            Dv[4*q+3] = acc[4*q+3] * x3;
        }
        packB();
        asm volatile("" ::: "memory");   // keep refill below the reads
        issueTile(pclamp(t0 + idx + DEPTH), idx & (DEPTH - 1));
    };

    auto initConsume = [&](int idx) {    // p := exp(e_t)
        asm volatile("s_waitcnt vmcnt(28)" ::: "memory");
        float4 bu[4];
        readFrag(idx & (DEPTH - 1), bu);
        #pragma unroll
        for (int q = 0; q < 4; ++q) {
            Dv[4*q+0] = __expf(bu[q].x);
            Dv[4*q+1] = __expf(bu[q].y);
            Dv[4*q+2] = __expf(bu[q].z);
            Dv[4*q+3] = __expf(bu[q].w);
        }
        packB();
        asm volatile("" ::: "memory");
        issueTile(pclamp(t0 + idx + DEPTH), idx & (DEPTH - 1));
    };

    auto renorm = [&]() {
        float m0 = fmaxf(fmaxf(Dv[0], Dv[1]),  fmaxf(Dv[2],  Dv[3]));
        float m1 = fmaxf(fmaxf(Dv[4], Dv[5]),  fmaxf(Dv[6],  Dv[7]));
        float m2 = fmaxf(fmaxf(Dv[8], Dv[9]),  fmaxf(Dv[10], Dv[11]));
        float m3 = fmaxf(fmaxf(Dv[12],Dv[13]), fmaxf(Dv[14], Dv[15]));
        float m  = fmaxf(fmaxf(m0, m1), fmaxf(m2, m3));
        m = fmaxf(m, __shfl_xor(m, 32, 64));
        int k = (int)((__float_as_uint(m) >> 23) & 0xffu) - 126;
        offF += (float)k * LN2f;
        adj = -(float)k;
    };

    auto sumD = [&]() {
        float t = 0.f;
        #pragma unroll
        for (int r = 0; r < 16; ++r) t += Dv[r];
        t += __shfl_xor(t, 32, 64);
        return t;
    };

    // ---- prologue: fill DEPTH tiles (32 outstanding gload_lds)
    #pragma unroll
    for (int i = 0; i < DEPTH; ++i) issueTile(pclamp(t0 + i), i);

    int idx = 0;
    (void)nsteps;
    if (s == 0) {
        initConsume(idx); ++idx;                  // t = 0: alpha_0 = e_0
        #pragma unroll
        for (int u = 1; u < 8; ++u) { stepConsume(idx, 0.f); ++idx; }
        renorm();
        #pragma unroll 1
        for (int blk = 0; blk < 3; ++blk) {       // t = 8..31
            #pragma unroll
            for (int u = 0; u < 8; ++u) { stepConsume(idx, (u == 0) ? adj : 0.f); ++idx; }
            adj = 0.f;
            if (blk < 2) renorm();
        }
    } else {
        initConsume(idx); ++idx;                  // warm-up start
        #pragma unroll
        for (int u = 1; u < 8; ++u) { stepConsume(idx, 0.f); ++idx; }
        renorm();
        #pragma unroll
        for (int u = 0; u < 8; ++u) { stepConsume(idx, (u == 0) ? adj : 0.f); ++idx; }
        adj = 0.f;
        float S = sumD();                         // boundary sum-normalize
        adj = -__log2f(S);
        offF = 0.f;
        #pragma unroll 1
        for (int blk = 0; blk < 4; ++blk) {       // the real 32 steps
            #pragma unroll
            for (int u = 0; u < 8; ++u) { stepConsume(idx, (u == 0) ? adj : 0.f); ++idx; }
            adj = 0.f;
            if (blk < 3) renorm();
        }
    }

    float Sf = sumD();
    float delta = offF + __logf(Sf);
    if (lane < 32) {
        dDelta[s * Bn + b] = delta;
    }
}

// Per-batch gold-path score + msum + last-emission + per-batch logZ partial sum.
// One block per batch; gathers are batch-local (contiguous 1 KB windows) and run
// at high parallelism instead of polluting the serial scan.
__global__ __launch_bounds__(256) void crf_score(
    const float* __restrict__ emis, const float* __restrict__ trans,
    const int* __restrict__ tags, const int* __restrict__ mask,
    const float* __restrict__ dDelta, float* __restrict__ dVal)
{
    __shared__ float Tl[Cn * Cn];
    __shared__ float redS[4];
    __shared__ int   redM[4];
    const int b = blockIdx.x;
    const int tid = threadIdx.x;
    for (int i = tid; i < Cn * Cn; i += 256) Tl[i] = trans[i];
    __syncthreads();

    const size_t tB = (size_t)b * Ln;
    const size_t eb = (size_t)b * Ln * Cn;
    const int t0 = tid * 8;

    int tg[9], mk[9];
    {
        int4 a0 = *(const int4*)(tags + tB + t0);
        int4 a1 = *(const int4*)(tags + tB + t0 + 4);
        int4 c0 = *(const int4*)(mask + tB + t0);
        int4 c1 = *(const int4*)(mask + tB + t0 + 4);
        tg[0]=a0.x; tg[1]=a0.y; tg[2]=a0.z; tg[3]=a0.w;
        tg[4]=a1.x; tg[5]=a1.y; tg[6]=a1.z; tg[7]=a1.w;
        mk[0]=c0.x; mk[1]=c0.y; mk[2]=c0.z; mk[3]=c0.w;
        mk[4]=c1.x; mk[5]=c1.y; mk[6]=c1.z; mk[7]=c1.w;
        tg[8] = (t0 + 8 < Ln) ? tags[tB + t0 + 8] : 0;
        mk[8] = (t0 + 8 < Ln) ? mask[tB + t0 + 8] : 0;
    }

    float sc = 0.f; int ms = 0;
    #pragma unroll
    for (int u = 0; u < 8; ++u) {
        int t = t0 + u;
        ms += mk[u];
        if (t < Ln - 1) {
            sc += (float)mk[u]     * emis[eb + (size_t)t * Cn + tg[u]];   // emit(t)*mask[t]
            sc += (float)mk[u + 1] * Tl[(tg[u] << 5) + tg[u + 1]];        // T*mask[t+1]
        }
    }
    #pragma unroll
    for (int o = 32; o > 0; o >>= 1) {
        sc += __shfl_down(sc, o, 64);
        ms += __shfl_down(ms, o, 64);
    }
    if ((tid & 63) == 0) { redS[tid >> 6] = sc; redM[tid >> 6] = ms; }
    __syncthreads();

    if (tid < NSEG) {
        float lz = dDelta[(size_t)tid * Bn + b];
        #pragma unroll
        for (int o = 32; o > 0; o >>= 1) lz += __shfl_down(lz, o, 64);
        if (tid == 0) {
            float scT = redS[0] + redS[1] + redS[2] + redS[3];
            int   msT = redM[0] + redM[1] + redM[2] + redM[3];
            int last_idx = max(msT - 1, 0);
            int le_t     = max(msT, 1) - 1;
            int lt = tags[tB + last_idx];
            float le = emis[eb + (size_t)le_t * Cn + lt];
            dVal[b] = lz - (scT + le);
        }
    }
}

__global__ void crf_final(const float* __restrict__ dVal, float* __restrict__ out)
{
    __shared__ float red[8];
    int b = threadIdx.x;   // 512 threads = one per batch
    float val = dVal[b];
    #pragma unroll
    for (int o = 32; o > 0; o >>= 1) val += __shfl_down(val, o, 64);
    if ((b & 63) == 0) red[b >> 6] = val;
    __syncthreads();
    if (b == 0) {
        float t = 0.f;
        #pragma unroll
        for (int w = 0; w < 8; ++w) t += red[w];
        out[0] = t * (1.0f / (float)Bn);
    }
}

extern "C" void kernel_launch(void* const* d_in, const int* in_sizes, int n_in,
                              void* d_out, int out_size, void* d_ws, size_t ws_size,
                              hipStream_t stream)
{
    const float* emis  = (const float*)d_in[0];
    const float* trans = (const float*)d_in[1];
    const int*   tags  = (const int*)d_in[2];
    const int*   mask  = (const int*)d_in[3];
    float* wsf = (float*)d_ws;
    float* dDelta = wsf;                 // NSEG*Bn f32
    float* dVal   = wsf + NSEG * Bn;     // Bn f32
    crf_scan<<<(NGRP * NSEG) / WPB, 64 * WPB, 0, stream>>>(emis, trans, dDelta);
    crf_score<<<Bn, 256, 0, stream>>>(emis, trans, tags, mask, dDelta, dVal);
    crf_final<<<1, Bn, 0, stream>>>(dVal, (float*)d_out);
}

// Round 4
// 241.342 us; speedup vs baseline: 1.0346x; 1.0346x over previous
//
#include <hip/hip_runtime.h>
#include <stdint.h>

typedef short bf16x8 __attribute__((ext_vector_type(8)));
typedef float f32x16 __attribute__((ext_vector_type(16)));

#define LN2f  0.69314718055994530942f

constexpr int Bn = 512;
constexpr int Ln = 2048;
constexpr int Cn = 32;
constexpr int NSEG = 64;      // 1024 scan units
constexpr int SEGLEN = 32;    // Ln / NSEG
constexpr int WARM = 16;
constexpr int NGRP = 16;      // Bn / 32
constexpr int WPB  = 4;       // waves per block
constexpr int DEPTH = 8;      // emission tile pipeline depth (per wave, in LDS)

// pack two f32 -> one VGPR of two bf16 (round-half-away via +0x8000, then take high halves)
__device__ __forceinline__ uint32_t pack2_bf16(float lo, float hi) {
    uint32_t a = __float_as_uint(lo) + 0x8000u;
    uint32_t b = __float_as_uint(hi) + 0x8000u;
    return __builtin_amdgcn_perm(b, a, 0x07060302u);
}

__device__ __forceinline__ void gload16(const float* g, float* l) {
    __builtin_amdgcn_global_load_lds(
        (__attribute__((address_space(1))) void*)g,
        (__attribute__((address_space(3))) void*)l,
        16, 0, 0);
}

// crf_scan v4: exp moved OFF the serial chain.
// Rounds 0-3 established: per-wave step time ~1000-1400cy/CU regardless of
// occupancy, placement, memory source (LLC-warm == HBM speed), request pattern.
// All counters idle -> the stall is the step's own dependency braid:
// ds_read(120cy) -> fma -> 16x v_exp -> mul -> pack -> MFMA.
// Fix: register-stage E = exp(emis) two steps ahead (Eg[2][16]); the exp work
// for step i+2 runs in the shadow of step i's MFMAs. Chain per step is now just
// MFMA x2 -> 16 mul -> pack. Renorm/boundary scales Dv directly before pack
// (adj-folding deleted).
//
// LDS tile (per wave, per slot): T[row=batch 0..31][8 x 16B chunks], XOR-swizzled
// via pre-swizzled GLOBAL source address (both-sides-or-neither, r3 layout kept).
// Pipeline: gload tiles 8 ahead (vmcnt(20): tile i+2 complete at step i);
// ds_read tile i+2 at step i -> exp -> Eg; consume Eg at step i+2.
__global__ __launch_bounds__(256, 1) void crf_scan(
    const float* __restrict__ emis, const float* __restrict__ trans,
    float* __restrict__ dDelta)
{
    __shared__ float ELDS[WPB][DEPTH][1024];   // 128 KiB
    const int lane = threadIdx.x & 63;
    const int wid  = threadIdx.x >> 6;
    const int h    = lane >> 5;
    const int bl   = lane & 31;
    const int bl7  = bl & 7;
    const int unit = blockIdx.x * WPB + wid;   // 0..1023
    const int g    = unit & (NGRP - 1);
    const int s    = unit >> 4;                // 0..NSEG-1
    const int b    = g * 32 + bl;

    // per-lane global element offsets per load-instr q (pre-swizzled chunk index)
    uint32_t gqb[4];
    {
        const int lr = lane >> 3;      // 0..7
        const int lc = lane & 7;       // 0..7
        #pragma unroll
        for (int q = 0; q < 4; ++q) {
            int br = 8 * q + lr;               // batch-in-group = LDS row
            int sg = lc ^ lr;                  // pre-swizzled 16B-chunk index
            gqb[q] = (uint32_t)((g * 32 + br) * (Ln * Cn) + sg * 4);
        }
    }

    // Constant A fragments: A[m=bl][k'], k' = 8h + j; col(j) = 4h + (j&3) + 8*(j>>2) (+16 for A2)
    bf16x8 A1, A2;
    {
        float e1[8], e2[8];
        #pragma unroll
        for (int j = 0; j < 8; ++j) {
            int c1 = 4 * h + (j & 3) + 8 * (j >> 2);
            e1[j] = __expf(trans[bl * Cn + c1]);
            e2[j] = __expf(trans[bl * Cn + c1 + 16]);
        }
        union { uint32_t u[4]; bf16x8 v; } ua, ub;
        #pragma unroll
        for (int q = 0; q < 4; ++q) {
            ua.u[q] = pack2_bf16(e1[2*q], e1[2*q+1]);
            ub.u[q] = pack2_bf16(e2[2*q], e2[2*q+1]);
        }
        A1 = ua.v; A2 = ub.v;
    }

    const f32x16 zeroC = {0.f,0.f,0.f,0.f,0.f,0.f,0.f,0.f,0.f,0.f,0.f,0.f,0.f,0.f,0.f,0.f};

    f32x16 Dv;
    bf16x8 B1, B2;
    float  Eg[2][16];          // exp(emission) staged 2 steps ahead (static parity idx)
    float  offF = 0.f;

    const int t0 = (s == 0) ? 0 : s * SEGLEN - WARM;

    auto issueTile = [&](int t, int slot) {
        const float* gp = emis + (size_t)t * Cn;
        #pragma unroll
        for (int q = 0; q < 4; ++q)
            gload16(gp + gqb[q], &ELDS[wid][slot][q * 256]);
    };

    auto readRaw = [&](int slot, float4 (&bu)[4]) {
        #pragma unroll
        for (int q = 0; q < 4; ++q) {
            int c16 = (h + 2 * q) ^ bl7;
            bu[q] = *(const float4*)&ELDS[wid][slot][bl * 32 + c16 * 4];
        }
    };

    auto packB = [&]() {
        union { uint32_t u[4]; bf16x8 v; } p1, p2;
        #pragma unroll
        for (int q = 0; q < 4; ++q) {
            p1.u[q] = pack2_bf16(Dv[2*q],     Dv[2*q + 1]);
            p2.u[q] = pack2_bf16(Dv[8 + 2*q], Dv[8 + 2*q + 1]);
        }
        B1 = p1.v; B2 = p2.v;
    };

    auto sumD = [&]() {
        float t = 0.f;
        #pragma unroll
        for (int r = 0; r < 16; ++r) t += Dv[r];
        t += __shfl_xor(t, 32, 64);
        return t;
    };

    // mode: 0 none, 1 renorm (pow2 scale + offF), 2 boundary (sum-normalize, offF=0)
    // u is a compile-time literal via full unroll -> slot/parity indices static.
    auto step = [&](int u, bool isInit, int mode, int tIssue) {
        asm volatile("s_waitcnt vmcnt(20)" ::: "memory");
        float4 bu[4];
        readRaw((u + 2) & 7, bu);              // raw tile i+2
        const int par = u & 1;
        if (isInit) {
            #pragma unroll
            for (int r = 0; r < 16; ++r) Dv[r] = Eg[par][r];
        } else {
            f32x16 acc = __builtin_amdgcn_mfma_f32_32x32x16_bf16(A1, B1, zeroC, 0, 0, 0);
            acc = __builtin_amdgcn_mfma_f32_32x32x16_bf16(A2, B2, acc, 0, 0, 0);
            #pragma unroll
            for (int r = 0; r < 16; ++r) Dv[r] = acc[r] * Eg[par][r];
        }
        if (u == 7) {
            if (mode == 1) {
                float m0 = fmaxf(fmaxf(Dv[0], Dv[1]),  fmaxf(Dv[2],  Dv[3]));
                float m1 = fmaxf(fmaxf(Dv[4], Dv[5]),  fmaxf(Dv[6],  Dv[7]));
                float m2 = fmaxf(fmaxf(Dv[8], Dv[9]),  fmaxf(Dv[10], Dv[11]));
                float m3 = fmaxf(fmaxf(Dv[12],Dv[13]), fmaxf(Dv[14], Dv[15]));
                float m  = fmaxf(fmaxf(m0, m1), fmaxf(m2, m3));
                m = fmaxf(m, __shfl_xor(m, 32, 64));
                int k = (int)((__float_as_uint(m) >> 23) & 0xffu) - 126;
                offF += (float)k * LN2f;
                float sc = __uint_as_float((uint32_t)(127 - k) << 23);   // exact 2^-k
                #pragma unroll
                for (int r = 0; r < 16; ++r) Dv[r] *= sc;
            } else if (mode == 2) {
                float S = sumD();
                float inv = 1.0f / S;
                offF = 0.f;
                #pragma unroll
                for (int r = 0; r < 16; ++r) Dv[r] *= inv;
            }
        }
        packB();
        // off-chain: exp tile i+2 into Eg[par] (consumed at step i+2, same parity)
        #pragma unroll
        for (int q = 0; q < 4; ++q) {
            Eg[par][4*q+0] = __expf(bu[q].x);
            Eg[par][4*q+1] = __expf(bu[q].y);
            Eg[par][4*q+2] = __expf(bu[q].z);
            Eg[par][4*q+3] = __expf(bu[q].w);
        }
        // issue tile i+8 into slot i&7 (= u); its previous tile was reg-staged at i-2
        asm volatile("" ::: "memory");
        issueTile(min(tIssue, Ln - 1), u);
    };

    // ---- prologue: fill DEPTH tiles (32 outstanding gloads), reg-stage tiles 0,1
    #pragma unroll
    for (int i2 = 0; i2 < DEPTH; ++i2) issueTile(min(t0 + i2, Ln - 1), i2);
    asm volatile("s_waitcnt vmcnt(24)" ::: "memory");   // tiles 0,1 complete
    {
        float4 r0[4], r1[4];
        readRaw(0, r0);
        readRaw(1, r1);
        #pragma unroll
        for (int q = 0; q < 4; ++q) {
            Eg[0][4*q+0] = __expf(r0[q].x);  Eg[0][4*q+1] = __expf(r0[q].y);
            Eg[0][4*q+2] = __expf(r0[q].z);  Eg[0][4*q+3] = __expf(r0[q].w);
            Eg[1][4*q+0] = __expf(r1[q].x);  Eg[1][4*q+1] = __expf(r1[q].y);
            Eg[1][4*q+2] = __expf(r1[q].z);  Eg[1][4*q+3] = __expf(r1[q].w);
        }
    }

    if (s == 0) {
        // block 0: t = 0..7 (init at 0, renorm at 7)
        step(0, true, 0, t0 + 8);
        #pragma unroll
        for (int u = 1; u < 8; ++u) step(u, false, (u == 7) ? 1 : 0, t0 + u + 8);
        #pragma unroll 1
        for (int blk = 1; blk < 4; ++blk) {     // t = 8..31, renorm at 15,23
            const int base = blk * 8;
            #pragma unroll
            for (int u = 0; u < 8; ++u)
                step(u, false, (u == 7 && blk < 3) ? 1 : 0, t0 + base + u + 8);
        }
    } else {
        // warm block 0: t0..t0+7 (init, renorm at end)
        step(0, true, 0, t0 + 8);
        #pragma unroll
        for (int u = 1; u < 8; ++u) step(u, false, (u == 7) ? 1 : 0, t0 + u + 8);
        // warm block 1: t0+8..t0+15 ; boundary sum-normalize at end (t = seg start - 1)
        #pragma unroll
        for (int u = 0; u < 8; ++u) step(u, false, (u == 7) ? 2 : 0, t0 + 8 + u + 8);
        #pragma unroll 1
        for (int blk = 2; blk < 6; ++blk) {     // the real 32 steps, renorm at ends of blk 2,3,4
            const int base = blk * 8;
            #pragma unroll
            for (int u = 0; u < 8; ++u)
                step(u, false, (u == 7 && blk < 5) ? 1 : 0, t0 + base + u + 8);
        }
    }

    float Sf = sumD();
    float delta = offF + __logf(Sf);
    if (lane < 32) {
        dDelta[s * Bn + b] = delta;
    }
}

// Per-batch gold-path score + msum + last-emission + per-batch total (logZ - score).
__global__ __launch_bounds__(256) void crf_score(
    const float* __restrict__ emis, const float* __restrict__ trans,
    const int* __restrict__ tags, const int* __restrict__ mask,
    const float* __restrict__ dDelta, float* __restrict__ dVal)
{
    __shared__ float Tl[Cn * Cn];
    __shared__ float redS[4];
    __shared__ int   redM[4];
    const int b = blockIdx.x;
    const int tid = threadIdx.x;
    for (int i = tid; i < Cn * Cn; i += 256) Tl[i] = trans[i];
    __syncthreads();

    const size_t tB = (size_t)b * Ln;
    const size_t eb = (size_t)b * Ln * Cn;
    const int t0 = tid * 8;

    int tg[9], mk[9];
    {
        int4 a0 = *(const int4*)(tags + tB + t0);
        int4 a1 = *(const int4*)(tags + tB + t0 + 4);
        int4 c0 = *(const int4*)(mask + tB + t0);
        int4 c1 = *(const int4*)(mask + tB + t0 + 4);
        tg[0]=a0.x; tg[1]=a0.y; tg[2]=a0.z; tg[3]=a0.w;
        tg[4]=a1.x; tg[5]=a1.y; tg[6]=a1.z; tg[7]=a1.w;
        mk[0]=c0.x; mk[1]=c0.y; mk[2]=c0.z; mk[3]=c0.w;
        mk[4]=c1.x; mk[5]=c1.y; mk[6]=c1.z; mk[7]=c1.w;
        tg[8] = (t0 + 8 < Ln) ? tags[tB + t0 + 8] : 0;
        mk[8] = (t0 + 8 < Ln) ? mask[tB + t0 + 8] : 0;
    }

    float sc = 0.f; int ms = 0;
    #pragma unroll
    for (int u = 0; u < 8; ++u) {
        int t = t0 + u;
        ms += mk[u];
        if (t < Ln - 1) {
            sc += (float)mk[u]     * emis[eb + (size_t)t * Cn + tg[u]];
            sc += (float)mk[u + 1] * Tl[(tg[u] << 5) + tg[u + 1]];
        }
    }
    #pragma unroll
    for (int o = 32; o > 0; o >>= 1) {
        sc += __shfl_down(sc, o, 64);
        ms += __shfl_down(ms, o, 64);
    }
    if ((tid & 63) == 0) { redS[tid >> 6] = sc; redM[tid >> 6] = ms; }
    __syncthreads();

    if (tid < NSEG) {
        float lz = dDelta[(size_t)tid * Bn + b];
        #pragma unroll
        for (int o = 32; o > 0; o >>= 1) lz += __shfl_down(lz, o, 64);
        if (tid == 0) {
            float scT = redS[0] + redS[1] + redS[2] + redS[3];
            int   msT = redM[0] + redM[1] + redM[2] + redM[3];
            int last_idx = max(msT - 1, 0);
            int le_t     = max(msT, 1) - 1;
            int lt = tags[tB + last_idx];
            float le = emis[eb + (size_t)le_t * Cn + lt];
            dVal[b] = lz - (scT + le);
        }
    }
}

__global__ void crf_final(const float* __restrict__ dVal, float* __restrict__ out)
{
    __shared__ float red[8];
    int b = threadIdx.x;   // 512 threads = one per batch
    float val = dVal[b];
    #pragma unroll
    for (int o = 32; o > 0; o >>= 1) val += __shfl_down(val, o, 64);
    if ((b & 63) == 0) red[b >> 6] = val;
    __syncthreads();
    if (b == 0) {
        float t = 0.f;
        #pragma unroll
        for (int w = 0; w < 8; ++w) t += red[w];
        out[0] = t * (1.0f / (float)Bn);
    }
}

extern "C" void kernel_launch(void* const* d_in, const int* in_sizes, int n_in,
                              void* d_out, int out_size, void* d_ws, size_t ws_size,
                              hipStream_t stream)
{
    const float* emis  = (const float*)d_in[0];
    const float* trans = (const float*)d_in[1];
    const int*   tags  = (const int*)d_in[2];
    const int*   mask  = (const int*)d_in[3];
    float* wsf = (float*)d_ws;
    float* dDelta = wsf;                 // NSEG*Bn f32
    float* dVal   = wsf + NSEG * Bn;     // Bn f32
    crf_scan<<<(NGRP * NSEG) / WPB, 64 * WPB, 0, stream>>>(emis, trans, dDelta);
    crf_score<<<Bn, 256, 0, stream>>>(emis, trans, tags, mask, dDelta, dVal);
    crf_final<<<1, Bn, 0, stream>>>(dVal, (float*)d_out);
}